// Round 1
// baseline (219.788 us; speedup 1.0000x reference)
//
#include <hip/hip_runtime.h>
#include <hip/hip_bf16.h>

// Problem constants (from reference)
#define N_NODES 50000
#define N_EDGES 800000
#define EP (N_EDGES + N_NODES)   // edges incl. self loops = 850000
#define IN_C 128
#define HID 32
#define OUT_C 64
#define HEADS 4
#define NEG_SLOPE 0.2f

#define NPB 128                          // nodes per bucket (power of 2)
#define K_BUCKETS ((N_NODES + NPB - 1) / NPB)   // 391

typedef unsigned int uint32;
typedef __attribute__((ext_vector_type(8))) short bf16x8;   // MFMA A/B frag (4 VGPR)
typedef __attribute__((ext_vector_type(4))) float f32x4;    // MFMA C/D frag

__device__ __forceinline__ float bf_lo(uint32 u) { return __uint_as_float(u << 16); }
__device__ __forceinline__ float bf_hi(uint32 u) { return __uint_as_float(u & 0xffff0000u); }
// round-to-nearest-even f32 -> bf16 (no NaN inputs here)
__device__ __forceinline__ uint32 f2bf(float f) {
    uint32 u = __float_as_uint(f);
    return (u + 0x7fffu + ((u >> 16) & 1u)) >> 16;
}
__device__ __forceinline__ uint32 pack_bf2(float a, float b) {
    return f2bf(a) | (f2bf(b) << 16);
}

// ---------- init: bucket counts + attention vectors + MFMA B-fragments --------
__global__ __launch_bounds__(512) void k_init2(int* __restrict__ gcnt,
                                               const float* __restrict__ Wg,
                                               const float* __restrict__ ags,
                                               const float* __restrict__ agd,
                                               float* __restrict__ wals,
                                               float* __restrict__ wald,
                                               const float* __restrict__ W2,
                                               uint32* __restrict__ wgB,
                                               uint32* __restrict__ w2B) {
    int t = threadIdx.x;
    if (t < K_BUCKETS + 1) gcnt[t] = 0;
    if (t < 256) {
        int c = t & 127;
        int h = c >> 5, k = c & 31;
        const float* a = (t < 128) ? ags : agd;
        float acc = 0.f;
#pragma unroll
        for (int d = 0; d < 32; d++) acc += Wg[k * 128 + h * 32 + d] * a[h * 32 + d];
        if (t < 128) wals[c] = acc; else wald[c] = acc;
    }
    for (int i = t; i < 2048; i += 512) {
        int tile = i >> 8;            // 0..7 = T*4+kt
        int T = tile >> 2, kt = tile & 3;
        int r = i & 255;
        int L = r >> 2, di = r & 3;
        int k0 = kt * 32 + (L >> 4) * 8 + 2 * di;
        int k1 = k0 + 1;
        int n = T * 16 + (L & 15);
        float a = Wg[(k0 & 31) * 128 + (k0 >> 5) * 32 + n];
        float b = Wg[(k1 & 31) * 128 + (k1 >> 5) * 32 + n];
        wgB[i] = pack_bf2(a, b);
    }
    for (int i = t; i < 1024; i += 512) {
        int T = i >> 8;
        int r = i & 255;
        int L = r >> 2, di = r & 3;
        int k0 = (L >> 4) * 8 + 2 * di;
        int n = T * 16 + (L & 15);
        w2B[i] = pack_bf2(W2[k0 * 64 + n], W2[(k0 + 1) * 64 + n]);
    }
}

// ---------- CSR build via two-level bucket sort ----------

__global__ __launch_bounds__(256) void k_bcount(const int* __restrict__ ei,
                                                int* __restrict__ gcnt) {
    __shared__ int h[K_BUCKETS];
    int t = threadIdx.x;
    for (int i = t; i < K_BUCKETS; i += 256) h[i] = 0;
    __syncthreads();
    int base = blockIdx.x * 4096;
    int dd[16];
#pragma unroll
    for (int k = 0; k < 16; k++) {
        int e = base + k * 256 + t;
        dd[k] = (e < N_EDGES) ? ei[N_EDGES + e] : -1;
    }
#pragma unroll
    for (int k = 0; k < 16; k++)
        if (dd[k] >= 0) atomicAdd(&h[dd[k] >> 7], 1);
    __syncthreads();
    for (int i = t; i < K_BUCKETS; i += 256)
        if (h[i]) atomicAdd(&gcnt[i], h[i]);
}

__global__ __launch_bounds__(512) void k_bscan(const int* __restrict__ gcnt,
                                               int* __restrict__ gbase,
                                               int* __restrict__ gcursor) {
    __shared__ int sd[512];
    int t = threadIdx.x;
    int v = (t < K_BUCKETS) ? gcnt[t] : 0;
    sd[t] = v;
    __syncthreads();
    for (int off = 1; off < 512; off <<= 1) {
        int x = (t >= off) ? sd[t - off] : 0;
        __syncthreads();
        sd[t] += x;
        __syncthreads();
    }
    if (t < K_BUCKETS) {
        int excl = sd[t] - v;
        gbase[t] = excl;
        gcursor[t] = excl;
    }
    if (t == 0) gbase[K_BUCKETS] = sd[K_BUCKETS - 1];
}

__global__ __launch_bounds__(256) void k_bucket(const int* __restrict__ ei,
                                                int* __restrict__ gcursor,
                                                uint32* __restrict__ gpairs) {
    __shared__ int cnt[K_BUCKETS];
    __shared__ int bas[K_BUCKETS];
    int t = threadIdx.x;
    for (int i = t; i < K_BUCKETS; i += 256) cnt[i] = 0;
    __syncthreads();
    int base = blockIdx.x * 2048;
    int ss[8], dd[8], ml[8];
#pragma unroll
    for (int k = 0; k < 8; k++) {
        int e = base + k * 256 + t;
        ss[k] = (e < N_EDGES) ? ei[e] : -1;
        dd[k] = (e < N_EDGES) ? ei[N_EDGES + e] : 0;
    }
#pragma unroll
    for (int k = 0; k < 8; k++)
        if (ss[k] >= 0) ml[k] = atomicAdd(&cnt[dd[k] >> 7], 1);
    __syncthreads();
    for (int i = t; i < K_BUCKETS; i += 256)
        bas[i] = cnt[i] ? atomicAdd(&gcursor[i], cnt[i]) : 0;
    __syncthreads();
#pragma unroll
    for (int k = 0; k < 8; k++)
        if (ss[k] >= 0)
            gpairs[bas[dd[k] >> 7] + ml[k]] = ((uint32)ss[k] << 7) | (uint32)(dd[k] & 127);
}

// k_node: CSR finalize per 128-node bucket + per-bucket degree sort -> perm.
// perm groups similar-degree nodes so that gather waves (2 or 4 nodes/wave)
// run near-uniform edge-loop trip counts (kills exec-mask divergence waste).
__global__ __launch_bounds__(256) void k_node(const uint32* __restrict__ gpairs,
                                              const int* __restrict__ gbase,
                                              int* __restrict__ offs,
                                              float* __restrict__ dinv,
                                              int* __restrict__ srcs,
                                              int* __restrict__ perm) {
    __shared__ int cnt[NPB];
    __shared__ int scn[NPB];
    __shared__ int cur[NPB];
    __shared__ unsigned skey[NPB];
    int t = threadIdx.x;
    int b = blockIdx.x;
    int lo = b << 7;
    int nn = N_NODES - lo; if (nn > NPB) nn = NPB;
    int pb = gbase[b], pe = gbase[b + 1];
    if (t < NPB) cnt[t] = 0;
    __syncthreads();
    for (int i = pb + t; i < pe; i += 256)
        atomicAdd(&cnt[gpairs[i] & 127], 1);
    __syncthreads();
    if (t < NPB) scn[t] = cnt[t];
    __syncthreads();
    for (int off = 1; off < NPB; off <<= 1) {
        int x = 0;
        if (t >= off && t < NPB) x = scn[t - off];
        __syncthreads();
        if (t < NPB) scn[t] += x;
        __syncthreads();
    }
    if (t < nn) {
        int excl = scn[t] - cnt[t];
        int o = pb + excl + lo + t;
        offs[lo + t] = o;
        cur[t] = o;
        dinv[lo + t] = rsqrtf((float)(cnt[t] + 1));
        srcs[pb + scn[t] + lo + t] = lo + t;   // self-loop at last slot
    }
    if (b == K_BUCKETS - 1 && t == 0) offs[N_NODES] = pe + N_NODES;
    __syncthreads();
    for (int i = pb + t; i < pe; i += 256) {
        uint32 u = gpairs[i];
        int pos = atomicAdd(&cur[u & 127], 1);
        srcs[pos] = (int)(u >> 7);
    }
    // ---- degree sort (bitonic over 128 slots, key = deg<<7 | slot) ----
    if (t < NPB)
        skey[t] = (t < nn) ? (((unsigned)cnt[t] << 7) | (unsigned)t)
                           : (0x7fffff80u | (unsigned)t);
    __syncthreads();
    for (int k = 2; k <= NPB; k <<= 1) {
        for (int jj = k >> 1; jj > 0; jj >>= 1) {
            if (t < NPB) {
                int ixj = t ^ jj;
                if (ixj > t) {
                    unsigned a = skey[t], bb = skey[ixj];
                    if (((t & k) == 0) ? (a > bb) : (a < bb)) {
                        skey[t] = bb; skey[ixj] = a;
                    }
                }
            }
            __syncthreads();
        }
    }
    if (t < nn) perm[lo + t] = lo + (int)(skey[t] & 127u);
}

// ---------- GCN1: xw1 = bf16( (x @ W1) * dinv[row] ), float2-LDS weights ------
__global__ __launch_bounds__(256) void k_gemm1(const float* __restrict__ x,
                                               const float* __restrict__ W1,
                                               const float* __restrict__ dinv,
                                               uint32* __restrict__ xw1) {
    __shared__ float wl[IN_C * HID];   // as float2[k2][f]
    __shared__ float xl[8 * IN_C];
    int t = threadIdx.x;
    for (int i = t; i < IN_C * HID; i += 256) {
        int k = i >> 5, f = i & 31;
        wl[(k >> 1) * 64 + f * 2 + (k & 1)] = W1[i];
    }
    int nb = blockIdx.x * 8;
    const float4* x4 = (const float4*)(x + (size_t)nb * IN_C);
    ((float4*)xl)[t] = x4[t];
    __syncthreads();
    int g = t >> 5, f = t & 31;
    const float2* xr = (const float2*)(xl + g * IN_C);
    const float2* wp = (const float2*)wl;
    float acc = 0.f;
#pragma unroll 16
    for (int k2 = 0; k2 < 64; k2++) {
        float2 xv = xr[k2];
        float2 wv = wp[k2 * 32 + f];
        acc += xv.x * wv.x + xv.y * wv.y;
    }
    float v = acc * dinv[nb + g];
    float vn = __shfl_xor(v, 1, 64);
    if ((f & 1) == 0) xw1[(size_t)(nb + g) * 16 + (f >> 1)] = pack_bf2(v, vn);
}

// ---------- GCN1 aggregate -> per-node 128B record ----------
// rec[n] (128B aligned): [0:64) h1 as 16 packed-bf16 words (cache line 0),
// [64:80) als float4 (raw src-attention logits), [80:96) ald float4.
// exp/leaky moved into k_gat_agg (saves one float4 load per edge there).
__global__ __launch_bounds__(256) void k_gather1(const uint32* __restrict__ xw1,
                                                 const int* __restrict__ offs,
                                                 const int* __restrict__ srcs,
                                                 const int* __restrict__ perm,
                                                 const float* __restrict__ dinv,
                                                 const float* __restrict__ b1,
                                                 const float* __restrict__ wals,
                                                 const float* __restrict__ wald,
                                                 char* __restrict__ rec) {
    int t = threadIdx.x;
    int l16 = t & 15;
    int n = perm[blockIdx.x * 16 + (t >> 4)];
    int s0 = offs[n], s1 = offs[n + 1];
    const char* xb = (const char*)xw1 + l16 * 4;
    float a0 = 0.f, a1 = 0.f, a2 = 0.f, a3 = 0.f;
    float a4 = 0.f, a5 = 0.f, a6 = 0.f, a7 = 0.f;
    int j = s0;
    for (; j + 3 < s1; j += 4) {     // 4 independent gather chains
        uint32 uA = *(const uint32*)(xb + ((uint32)srcs[j] << 6));
        uint32 uB = *(const uint32*)(xb + ((uint32)srcs[j + 1] << 6));
        uint32 uC = *(const uint32*)(xb + ((uint32)srcs[j + 2] << 6));
        uint32 uD = *(const uint32*)(xb + ((uint32)srcs[j + 3] << 6));
        a0 += bf_lo(uA); a1 += bf_hi(uA);
        a2 += bf_lo(uB); a3 += bf_hi(uB);
        a4 += bf_lo(uC); a5 += bf_hi(uC);
        a6 += bf_lo(uD); a7 += bf_hi(uD);
    }
    for (; j < s1; ++j) {
        uint32 uA = *(const uint32*)(xb + ((uint32)srcs[j] << 6));
        a0 += bf_lo(uA); a1 += bf_hi(uA);
    }
    float dn = dinv[n];
    float2 b = ((const float2*)b1)[l16];
    float vx = ((a0 + a2) + (a4 + a6)) * dn + b.x;
    float vy = ((a1 + a3) + (a5 + a7)) * dn + b.y;
    vx = vx > 0.f ? vx : 0.f;
    vy = vy > 0.f ? vy : 0.f;
    char* rn = rec + (size_t)n * 128;
    *(uint32*)(rn + l16 * 4) = pack_bf2(vx, vy);

    float ps0, ps1, ps2, ps3, pd0, pd1, pd2, pd3;
    {
        float2 w0 = ((const float2*)wals)[0 * 16 + l16];
        float2 w1 = ((const float2*)wals)[1 * 16 + l16];
        float2 w2 = ((const float2*)wals)[2 * 16 + l16];
        float2 w3 = ((const float2*)wals)[3 * 16 + l16];
        ps0 = vx * w0.x + vy * w0.y;
        ps1 = vx * w1.x + vy * w1.y;
        ps2 = vx * w2.x + vy * w2.y;
        ps3 = vx * w3.x + vy * w3.y;
        float2 u0 = ((const float2*)wald)[0 * 16 + l16];
        float2 u1 = ((const float2*)wald)[1 * 16 + l16];
        float2 u2 = ((const float2*)wald)[2 * 16 + l16];
        float2 u3 = ((const float2*)wald)[3 * 16 + l16];
        pd0 = vx * u0.x + vy * u0.y;
        pd1 = vx * u1.x + vy * u1.y;
        pd2 = vx * u2.x + vy * u2.y;
        pd3 = vx * u3.x + vy * u3.y;
    }
#pragma unroll
    for (int m = 1; m < 16; m <<= 1) {
        ps0 += __shfl_xor(ps0, m, 16); ps1 += __shfl_xor(ps1, m, 16);
        ps2 += __shfl_xor(ps2, m, 16); ps3 += __shfl_xor(ps3, m, 16);
        pd0 += __shfl_xor(pd0, m, 16); pd1 += __shfl_xor(pd1, m, 16);
        pd2 += __shfl_xor(pd2, m, 16); pd3 += __shfl_xor(pd3, m, 16);
    }
    if (l16 == 0) {
        float4* r4 = (float4*)rn;
        r4[4] = make_float4(ps0, ps1, ps2, ps3);   // als
        r4[5] = make_float4(pd0, pd1, pd2, pd3);   // ald
    }
}

// ---------- Fused GAT: record edge aggregate + MFMA 128->32 post-GEMM ---------
// 512 threads = 16 nodes x 32 lanes. Per edge: w_h = exp(leaky(als_src+ald_dst)).
__global__ __launch_bounds__(512) void k_gat_agg(const char* __restrict__ rec,
                                                 const int* __restrict__ offs,
                                                 const int* __restrict__ srcs,
                                                 const int* __restrict__ perm,
                                                 const uint32* __restrict__ wgB,
                                                 const float* __restrict__ bg,
                                                 const float* __restrict__ dinv,
                                                 uint32* __restrict__ h2s) {
    __shared__ __align__(16) uint32 gl[16][64];  // packed g per node: 4 KB
    int t = threadIdx.x;
    int l32 = t & 31;
    int g8 = t >> 5;             // node slot 0..15
    int n = perm[blockIdx.x * 16 + g8];
    int l16 = l32 & 15;
    int par = l32 >> 4;          // edge parity this lane gathers
    int s0 = offs[n], s1 = offs[n + 1];
    float4 dv = ((const float4*)(rec + (size_t)n * 128))[5];  // ald of dst
    uint32 hoff = l16 * 4;       // lane's h1 word offset within record

    float g00 = 0.f, g01 = 0.f, g10 = 0.f, g11 = 0.f;
    float g20 = 0.f, g21 = 0.f, g30 = 0.f, g31 = 0.f;
    float ss0 = 0.f, ss1 = 0.f, ss2 = 0.f, ss3 = 0.f;

#define GAT_EDGE(J)                                                            \
    {                                                                          \
        uint32 off = (uint32)srcs[J] << 7;                                     \
        float4 ev = *(const float4*)(rec + off + 64);                          \
        uint32 u = *(const uint32*)(rec + off + hoff);                         \
        float flo = bf_lo(u), fhi = bf_hi(u);                                  \
        float tt, w;                                                           \
        tt = ev.x + dv.x; w = __expf(fmaxf(tt, NEG_SLOPE * tt));               \
        ss0 += w; g00 += w * flo; g01 += w * fhi;                              \
        tt = ev.y + dv.y; w = __expf(fmaxf(tt, NEG_SLOPE * tt));               \
        ss1 += w; g10 += w * flo; g11 += w * fhi;                              \
        tt = ev.z + dv.z; w = __expf(fmaxf(tt, NEG_SLOPE * tt));               \
        ss2 += w; g20 += w * flo; g21 += w * fhi;                              \
        tt = ev.w + dv.w; w = __expf(fmaxf(tt, NEG_SLOPE * tt));               \
        ss3 += w; g30 += w * flo; g31 += w * fhi;                              \
    }

    int j = s0 + par;
    for (; j + 2 < s1; j += 4) {   // unroll 2 for MLP
        GAT_EDGE(j);
        GAT_EDGE(j + 2);
    }
    if (j < s1) GAT_EDGE(j);
#undef GAT_EDGE

    // combine edge-parity halves (lanes l32 ^ 16)
    ss0 += __shfl_xor(ss0, 16, 64); ss1 += __shfl_xor(ss1, 16, 64);
    ss2 += __shfl_xor(ss2, 16, 64); ss3 += __shfl_xor(ss3, 16, 64);
    g00 += __shfl_xor(g00, 16, 64); g01 += __shfl_xor(g01, 16, 64);
    g10 += __shfl_xor(g10, 16, 64); g11 += __shfl_xor(g11, 16, 64);
    g20 += __shfl_xor(g20, 16, 64); g21 += __shfl_xor(g21, 16, 64);
    g30 += __shfl_xor(g30, 16, 64); g31 += __shfl_xor(g31, 16, 64);
    float i0 = 0.25f / ss0, i1 = 0.25f / ss1, i2 = 0.25f / ss2, i3 = 0.25f / ss3;
    if (l32 < 16) {
        gl[g8][0 * 16 + l16] = pack_bf2(g00 * i0, g01 * i0);
        gl[g8][1 * 16 + l16] = pack_bf2(g10 * i1, g11 * i1);
        gl[g8][2 * 16 + l16] = pack_bf2(g20 * i2, g21 * i2);
        gl[g8][3 * 16 + l16] = pack_bf2(g30 * i3, g31 * i3);
    }
    __syncthreads();
    if (t < 64) {
        int L = t;
        int mA = L & 15;          // A-operand row (node slot) for this lane
        int quad = L >> 4;
        int nbase = blockIdx.x * 16;
        int pn[4];
        float dns[4];
#pragma unroll
        for (int r = 0; r < 4; r++) {
            pn[r] = perm[nbase + quad * 4 + r];
            dns[r] = dinv[pn[r]];
        }
#pragma unroll
        for (int T = 0; T < 2; T++) {
            f32x4 acc = {0.f, 0.f, 0.f, 0.f};
#pragma unroll
            for (int kt = 0; kt < 4; kt++) {
                bf16x8 af = *(const bf16x8*)&gl[mA][kt * 16 + quad * 4];
                bf16x8 bf = *(const bf16x8*)(wgB + (size_t)((T * 4 + kt) * 64 + L) * 4);
                acc = __builtin_amdgcn_mfma_f32_16x16x32_bf16(af, bf, acc, 0, 0, 0);
            }
            int d = T * 16 + (L & 15);    // D col = lane&15 (output channel)
            float bgd = bg[d];
#pragma unroll
            for (int r = 0; r < 4; r++) {
                float v = acc[r] + bgd;
                v = v > 0.f ? v : 0.f;
                v *= dns[r];
                float vn = __shfl_xor(v, 1, 64);
                if ((d & 1) == 0)
                    h2s[(size_t)pn[r] * 16 + (d >> 1)] = pack_bf2(v, vn);
            }
        }
    }
}

// ---------- Fused GCN2: edge aggregate + MFMA 32->64 output GEMM --------------
__global__ __launch_bounds__(256) void k_gather2(const uint32* __restrict__ h2s,
                                                 const int* __restrict__ offs,
                                                 const int* __restrict__ srcs,
                                                 const int* __restrict__ perm,
                                                 const uint32* __restrict__ w2B,
                                                 const float* __restrict__ dinv,
                                                 const float* __restrict__ b2,
                                                 float* __restrict__ out) {
    __shared__ __align__(16) uint32 gbf[16][16]; // packed g2: 1 KB
    int t = threadIdx.x;
    int l16 = t & 15;
    int g16 = t >> 4;
    int n = perm[blockIdx.x * 16 + g16];
    int s0 = offs[n], s1 = offs[n + 1];
    const char* xb = (const char*)h2s + l16 * 4;
    float a0 = 0.f, a1 = 0.f, a2 = 0.f, a3 = 0.f;
    float a4 = 0.f, a5 = 0.f, a6 = 0.f, a7 = 0.f;
    int j = s0;
    for (; j + 3 < s1; j += 4) {     // 4 independent gather chains
        uint32 uA = *(const uint32*)(xb + ((uint32)srcs[j] << 6));
        uint32 uB = *(const uint32*)(xb + ((uint32)srcs[j + 1] << 6));
        uint32 uC = *(const uint32*)(xb + ((uint32)srcs[j + 2] << 6));
        uint32 uD = *(const uint32*)(xb + ((uint32)srcs[j + 3] << 6));
        a0 += bf_lo(uA); a1 += bf_hi(uA);
        a2 += bf_lo(uB); a3 += bf_hi(uB);
        a4 += bf_lo(uC); a5 += bf_hi(uC);
        a6 += bf_lo(uD); a7 += bf_hi(uD);
    }
    for (; j < s1; ++j) {
        uint32 uA = *(const uint32*)(xb + ((uint32)srcs[j] << 6));
        a0 += bf_lo(uA); a1 += bf_hi(uA);
    }
    gbf[g16][l16] = pack_bf2((a0 + a2) + (a4 + a6), (a1 + a3) + (a5 + a7));
    __syncthreads();
    if (t < 64) {
        int L = t;
        int quad = L >> 4;
        int nbase = blockIdx.x * 16;
        int pn[4];
        float dns[4];
#pragma unroll
        for (int r = 0; r < 4; r++) {
            pn[r] = perm[nbase + quad * 4 + r];
            dns[r] = dinv[pn[r]];
        }
        bf16x8 af = *(const bf16x8*)&gbf[L & 15][quad * 4];
#pragma unroll
        for (int T = 0; T < 4; T++) {
            bf16x8 bf = *(const bf16x8*)(w2B + (size_t)(T * 64 + L) * 4);
            f32x4 acc = {0.f, 0.f, 0.f, 0.f};
            acc = __builtin_amdgcn_mfma_f32_16x16x32_bf16(af, bf, acc, 0, 0, 0);
            int d = T * 16 + (L & 15);
            float b2d = b2[d];
#pragma unroll
            for (int r = 0; r < 4; r++) {
                out[(size_t)pn[r] * OUT_C + d] = acc[r] * dns[r] + b2d;
            }
        }
    }
}

extern "C" void kernel_launch(void* const* d_in, const int* in_sizes, int n_in,
                              void* d_out, int out_size, void* d_ws, size_t ws_size,
                              hipStream_t stream) {
    const float* x   = (const float*)d_in[0];
    const int*   ei  = (const int*)d_in[1];   // int64 in reference -> int32 from harness
    const float* W1  = (const float*)d_in[2];
    const float* b1  = (const float*)d_in[3];
    const float* Wg  = (const float*)d_in[4];
    const float* ags = (const float*)d_in[5];
    const float* agd = (const float*)d_in[6];
    const float* bg  = (const float*)d_in[7];
    const float* W2  = (const float*)d_in[8];
    const float* b2  = (const float*)d_in[9];
    float* out = (float*)d_out;

    char* p = (char*)d_ws;
    auto alloc = [&](size_t bytes) -> void* {
        void* r = (void*)p;
        p += (bytes + 255) & ~(size_t)255;
        return r;
    };
    float*  dinv    = (float*)alloc((size_t)N_NODES * 4);
    int*    offs    = (int*)  alloc((size_t)(N_NODES + 1) * 4);
    int*    gcnt    = (int*)  alloc((size_t)(K_BUCKETS + 1) * 4);
    int*    gbase   = (int*)  alloc((size_t)(K_BUCKETS + 1) * 4);
    int*    gcursor = (int*)  alloc((size_t)(K_BUCKETS + 1) * 4);
    int*    srcs    = (int*)  alloc((size_t)EP * 4);
    uint32* gpairs  = (uint32*)alloc((size_t)N_EDGES * 4);
    uint32* xw1     = (uint32*)alloc((size_t)N_NODES * 16 * 4);
    char*   rec     = (char*) alloc((size_t)N_NODES * 128);
    float*  wals    = (float*)alloc(128 * 4);
    float*  wald    = (float*)alloc(128 * 4);
    uint32* wgB     = (uint32*)alloc(2048 * 4);
    uint32* w2B     = (uint32*)alloc(1024 * 4);
    uint32* h2s     = (uint32*)alloc((size_t)N_NODES * 16 * 4);
    int*    perm    = (int*)  alloc((size_t)N_NODES * 4);

    // init + CSR build (two-level bucket sort) + degree-sorted node perm
    k_init2<<<1, 512, 0, stream>>>(gcnt, Wg, ags, agd, wals, wald, W2, wgB, w2B);
    k_bcount<<<(N_EDGES + 4095) / 4096, 256, 0, stream>>>(ei, gcnt);
    k_bscan<<<1, 512, 0, stream>>>(gcnt, gbase, gcursor);
    k_bucket<<<(N_EDGES + 2047) / 2048, 256, 0, stream>>>(ei, gcursor, gpairs);
    k_node<<<K_BUCKETS, 256, 0, stream>>>(gpairs, gbase, offs, dinv, srcs, perm);

    // GCN1
    k_gemm1<<<N_NODES / 8, 256, 0, stream>>>(x, W1, dinv, xw1);
    k_gather1<<<N_NODES / 16, 256, 0, stream>>>(xw1, offs, srcs, perm, dinv, b1,
                                                wals, wald, rec);

    // GAT: record edge aggregate + MFMA post-GEMM
    k_gat_agg<<<N_NODES / 16, 512, 0, stream>>>(rec, offs, srcs, perm, wgB, bg,
                                                dinv, h2s);

    // GCN2: edge aggregate + MFMA output GEMM
    k_gather2<<<N_NODES / 16, 256, 0, stream>>>(h2s, offs, srcs, perm, w2B,
                                                dinv, b2, out);
}